// Round 12
// baseline (171.761 us; speedup 1.0000x reference)
//
#include <hip/hip_runtime.h>

#define B_DIM 8
#define N_DIM 2048
#define C_DIM 256
#define K_SEL 1024

typedef __attribute__((ext_vector_type(8))) short short8;
typedef __attribute__((ext_vector_type(4))) float f32x4;

__device__ __forceinline__ unsigned int bf16rne(float x) {
  unsigned int u = __float_as_uint(x);
  return (u + 0x7fffu + ((u >> 16) & 1u)) >> 16;
}

// ---------------- FUSED LayerNorm + down-GEMM + w-chain (+ prep_w2 tail blocks) ----------------
// v13: CU-level LDS budget analysis: at 8 waves/CU, 3 ds_read_b128/kk/wave = 288 LDS
// cyc/kk/CU > 128 VALU cyc/SIMD/kk -> the GEMM phase was LDS-PIPE-bound (floor 30.7us,
// matches every measured 45-49us GEMM since round 0). Fix: A-consume via ONE
// ds_read_b32 per 8-kk group per lane + v_readlane broadcast (v7-verified bit-exact
// path; compile-time lane index). LDS drops to ~102 cyc/kk/CU < VALU 160 -> VALU-bound.
// As staging, FMA chain order (ascending k, single chain per (m,c)), LN phases, fbuf,
// epilogue, w-chain all byte-identical -> bit-exact w, top-k safe.
__global__ void __launch_bounds__(256) ln_wgemm(
    const float* __restrict__ feat, const float* __restrict__ gamma,
    const float* __restrict__ beta, float* __restrict__ fbuf,
    const float* __restrict__ Wd1, const float* __restrict__ bd1,
    const float* __restrict__ Wd2, const float* __restrict__ bd2,
    float* __restrict__ wkey,
    const float* __restrict__ Wu1, const float* __restrict__ Wu2,
    unsigned short* __restrict__ Wu1P, unsigned short* __restrict__ Wu2P) {
  __shared__ __align__(16) float tile[256 * 32];       // 32 KB raw x, [c][m ^ (c&31)]
  __shared__ __align__(16) char smem2[2304 + 16640];   // As 16x36x4 | Bs 16x260x4
  __shared__ float murs[64];                           // mu[0:32], rs[32:64]
  __shared__ float gb[512];                            // gamma[0:256], beta[256:512]
  float (*As)[36] = (float (*)[36])smem2;
  float (*Bs)[260] = (float (*)[260])(smem2 + 2304);
  float* H = tile;                                     // 256x32 f32 = 32 KB alias

  const int t = threadIdx.x;

  // ---- prep_w2 tail blocks (verbatim body; independent of LN work) ----
  if (blockIdx.x >= 512) {
    const int g = blockIdx.x - 512;
    const float* W = (g < 8) ? Wu1 : Wu2;
    unsigned short* P = (g < 8) ? Wu1P : Wu2P;
    const int kc = g & 7, n = t;
    unsigned int packed[16];
#pragma unroll
    for (int i = 0; i < 16; ++i) {
      const float a = W[(((kc << 5) + 2 * i) << 8) + n];
      const float bq = W[(((kc << 5) + 2 * i + 1) << 8) + n];
      packed[i] = bf16rne(a) | (bf16rne(bq) << 16);
    }
    uint4* dst = (uint4*)(P + (((kc << 8) + n) << 5));
#pragma unroll
    for (int q = 0; q < 4; ++q)
      dst[q] = make_uint4(packed[4 * q], packed[4 * q + 1], packed[4 * q + 2], packed[4 * q + 3]);
    return;
  }

  const int m0 = blockIdx.x << 5;                      // 32 rows per block
  const int b = m0 >> 11, n0 = m0 & 2047;

  gb[t] = gamma[t];
  gb[256 + t] = beta[t];

  // phase 1: stage raw features
  const int cg = t >> 3, nl4 = (t & 7) << 2;           // cg 0..31, nl4 0..28
  for (int pass = 0; pass < 8; ++pass) {
    const int c = (pass << 5) + cg;
    const float4 v = *(const float4*)(feat + (((long)((b << 8) + c)) << 11) + n0 + nl4);
    const int sw = c & 31;
    float* row = tile + (c << 5);
    row[(nl4 + 0) ^ sw] = v.x; row[(nl4 + 1) ^ sw] = v.y;
    row[(nl4 + 2) ^ sw] = v.z; row[(nl4 + 3) ^ sw] = v.w;
  }
  __syncthreads();

  // phase 2: mean/var per row, numpy-bit-exact chains
  if (t < 32) {
    float acc = tile[t];
    for (int c = 1; c < 256; ++c) acc = __fadd_rn(acc, tile[(c << 5) + (t ^ (c & 31))]);
    const float mu = __fdiv_rn(acc, 256.0f);

    float pw[2];
#pragma unroll
    for (int blk = 0; blk < 2; ++blk) {
      const int c0 = blk << 7;
      float r8[8];
#pragma unroll
      for (int j = 0; j < 8; ++j) {
        float d = __fsub_rn(tile[((c0 + j) << 5) + (t ^ ((c0 + j) & 31))], mu);
        r8[j] = __fmul_rn(d, d);
      }
      for (int i = 8; i < 128; i += 8) {
#pragma unroll
        for (int j = 0; j < 8; ++j) {
          const int c = c0 + i + j;
          float d = __fsub_rn(tile[(c << 5) + (t ^ (c & 31))], mu);
          r8[j] = __fadd_rn(r8[j], __fmul_rn(d, d));
        }
      }
      pw[blk] = __fadd_rn(__fadd_rn(__fadd_rn(r8[0], r8[1]), __fadd_rn(r8[2], r8[3])),
                          __fadd_rn(__fadd_rn(r8[4], r8[5]), __fadd_rn(r8[6], r8[7])));
    }
    const float var = __fdiv_rn(__fadd_rn(pw[0], pw[1]), 256.0f);
    const float rs = __fdiv_rn(1.0f, __fsqrt_rn(__fadd_rn(var, 1e-6f)));
    murs[t] = mu;
    murs[32 + t] = rs;
  }
  __syncthreads();

  // phase 3: write fbuf (one column per thread; coalesced stores)
  {
    const int c = t;
    const float gac = gb[c], bec = gb[256 + c];
    const float* trow = tile + (c << 5);
    const int sw = c & 31;
    for (int r = 0; r < 32; ++r) {
      const float x = trow[r ^ sw];
      const float o = __fadd_rn(
          __fmul_rn(__fmul_rn(__fsub_rn(x, murs[r]), murs[32 + r]), gac), bec);
      fbuf[(((long)(m0 + r)) << 8) + c] = o;
    }
  }

  // phase 4: K-loop; As staged from tile (normalize folded), A-consume via readlane
  const int rowT = t >> 6, colT = t & 63;
  const int lane = t & 63;
  const int ar = t & 31, kg4 = (t >> 5) << 2;
  const int bk = t >> 4, bc = (t & 15) << 4;
  const float mu_a = murs[ar], rs_a = murs[32 + ar];
  // lane l holds As[kg + (l>>3)][(rowT<<3) + (l&7)] per 8-kk group; <=2-way banks (free)
  const int as_off = (lane >> 3) * 36 + (rowT << 3) + (lane & 7);
  const float* Asf = (const float*)As;
  float acc[8][4] = {};

  for (int k0 = 0; k0 < 256; k0 += 16) {
    if (t < 128) {
#pragma unroll
      for (int q = 0; q < 4; ++q) {
        const int c = k0 + kg4 + q;
        const float x = tile[(c << 5) + (ar ^ (c & 31))];
        As[kg4 + q][ar] = __fadd_rn(
            __fmul_rn(__fmul_rn(__fsub_rn(x, mu_a), rs_a), gb[c]), gb[256 + c]);
      }
    }
    {
      const float* brow = Wd1 + (((k0 + bk) << 8) + bc);
      *(float4*)&Bs[bk][bc]      = *(const float4*)brow;
      *(float4*)&Bs[bk][bc + 4]  = *(const float4*)(brow + 4);
      *(float4*)&Bs[bk][bc + 8]  = *(const float4*)(brow + 8);
      *(float4*)&Bs[bk][bc + 12] = *(const float4*)(brow + 12);
    }
    __syncthreads();
#pragma unroll
    for (int kg = 0; kg < 16; kg += 8) {
      const float aread = Asf[as_off + kg * 36];   // 1 ds_read_b32 per 8 kk
#pragma unroll
      for (int k8 = 0; k8 < 8; ++k8) {             // k ascending: single FMA chain per (m,c)
        const float4 bq = *(const float4*)&Bs[kg + k8][colT << 2];
        const float bbv[4] = {bq.x, bq.y, bq.z, bq.w};
#pragma unroll
        for (int i = 0; i < 8; ++i) {
          const float aval = __uint_as_float(__builtin_amdgcn_readlane(
              __float_as_uint(aread), (k8 << 3) + i));
#pragma unroll
          for (int j = 0; j < 4; ++j)
            acc[i][j] = __fmaf_rn(aval, bbv[j], acc[i][j]);
        }
      }
    }
    __syncthreads();
  }

  // epilogue: bias + relu -> H[c][m] swizzled
  const float4 bd = *(const float4*)(bd1 + (colT << 2));
  const float ba[4] = {bd.x, bd.y, bd.z, bd.w};
#pragma unroll
  for (int i = 0; i < 8; ++i) {
    const int m = (rowT << 3) + i;
#pragma unroll
    for (int j = 0; j < 4; ++j) {
      const int c = (colT << 2) + j;
      H[(c << 5) + (m ^ ((c >> 2) & 31))] = fmaxf(__fadd_rn(acc[i][j], ba[j]), 0.0f);
    }
  }
  __syncthreads();

  // w-chain: ascending-c single FMA chain; key = (w+bd2)/0.1f
  if (t < 32) {
    float wa = 0.0f;
    for (int c = 0; c < 256; ++c)
      wa = __fmaf_rn(H[(c << 5) + (t ^ ((c >> 2) & 31))], Wd2[c], wa);
    const float w = __fadd_rn(wa, bd2[0]);
    wkey[m0 + t] = __fdiv_rn(w, 0.1f);
  }
}

// ---------------- per-batch top-K: register+shuffle bitonic (v12, verified) ----------------
__global__ void __launch_bounds__(1024) topk_kernel(
    const float* __restrict__ wv, const float* __restrict__ xyzs,
    int* __restrict__ idx_out, float* __restrict__ out_xyz,
    float* __restrict__ out_idx) {
  __shared__ unsigned long long vals[2048];
  const int b = blockIdx.x, t = threadIdx.x;

  unsigned long long a0, a1;
  {
    const float2 w2 = *(const float2*)(wv + (b << 11) + (t << 1));
    const unsigned int u0 = __float_as_uint(w2.x);
    const unsigned int p0 = ((int)u0 < 0) ? ~u0 : (u0 | 0x80000000u);
    a0 = (((unsigned long long)(~p0)) << 32) | (unsigned int)(2 * t);
    const unsigned int u1 = __float_as_uint(w2.y);
    const unsigned int p1 = ((int)u1 < 0) ? ~u1 : (u1 | 0x80000000u);
    a1 = (((unsigned long long)(~p1)) << 32) | (unsigned int)(2 * t + 1);
  }

  for (int k = 2; k <= 2048; k <<= 1) {
    for (int j = k >> 1; j >= 2; j >>= 1) {
      const int x = j >> 1;                       // partner-thread xor distance
      const bool up = (((t << 1) & k) == 0);
      unsigned long long p0, p1;
      if (j >= 128) {                             // cross-wave: via LDS
        vals[2 * t] = a0; vals[2 * t + 1] = a1;
        __syncthreads();
        p0 = vals[(2 * t) ^ j];
        p1 = vals[(2 * t + 1) ^ j];
        __syncthreads();                          // WAR guard for next LDS stage
      } else {                                    // intra-wave: x <= 32
        p0 = __shfl_xor(a0, x, 64);
        p1 = __shfl_xor(a1, x, 64);
      }
      const bool lower = ((t & x) == 0);
      const bool take_min = (lower == up);
      a0 = take_min ? (a0 < p0 ? a0 : p0) : (a0 > p0 ? a0 : p0);
      a1 = take_min ? (a1 < p1 ? a1 : p1) : (a1 > p1 ? a1 : p1);
    }
    {
      const bool up1 = (((t << 1) & k) == 0);
      if ((a0 > a1) == up1) { const unsigned long long tmp = a0; a0 = a1; a1 = tmp; }
    }
  }

  if (t < 512) {
    const int r0 = 2 * t, r1 = 2 * t + 1;
    const int s0 = (int)(a0 & 0xffffffffu);
    const int s1 = (int)(a1 & 0xffffffffu);
    idx_out[(b << 10) + r0] = s0;
    idx_out[(b << 10) + r1] = s1;
    out_idx[(b << 10) + r0] = (float)s0;
    out_idx[(b << 10) + r1] = (float)s1;
    const long o0 = ((long)((b << 10) + r0)) * 3;
    const long q0 = ((long)((b << 11) + s0)) * 3;
    out_xyz[o0] = xyzs[q0]; out_xyz[o0 + 1] = xyzs[q0 + 1]; out_xyz[o0 + 2] = xyzs[q0 + 2];
    const long o1 = ((long)((b << 10) + r1)) * 3;
    const long q1 = ((long)((b << 11) + s1)) * 3;
    out_xyz[o1] = xyzs[q1]; out_xyz[o1 + 1] = xyzs[q1 + 1]; out_xyz[o1 + 2] = xyzs[q1 + 2];
  }
}

// ---------------- fused up-branch: 256 blocks x 32 rows (v11, verified) ----------------
#define APITCH 264
#define BPITCH 40
__global__ void __launch_bounds__(256) up_mfma(
    const float* __restrict__ fbuf, const int* __restrict__ idxm,
    const unsigned short* __restrict__ Wu1P, const float* __restrict__ bu1,
    const unsigned short* __restrict__ Wu2P, const float* __restrict__ bu2,
    float* __restrict__ out_feat) {
  __shared__ __align__(16) char smem[32 * APITCH * 2 + 256 * BPITCH * 2 + 64 * 34 * 4 + 2048];
  unsigned short* As = (unsigned short*)smem;                       // 16896 B (later Hs)
  unsigned short* Bs = (unsigned short*)(smem + 32 * APITCH * 2);   // 20480 B
  float* T = (float*)(smem + 32 * APITCH * 2 + 256 * BPITCH * 2);   // 64x34 f32 = 8704 B
  float* bias1 = (float*)(smem + 32 * APITCH * 2 + 256 * BPITCH * 2 + 64 * 34 * 4);
  float* bias2 = bias1 + 256;

  const int t = threadIdx.x;
  const int m0 = blockIdx.x << 5;                      // 32 rows per block
  const int quad = (t >> 4) & 3, ln = t & 15, w = t >> 6;
  const int rb = w >> 1, ch = w & 1;

  bias1[t] = bu1[t];
  bias2[t] = bu2[t];

  // gather + cvt: As[r][c] bf16, r = t&31, cols (t>>5)*32..+32
  {
    const int r = t & 31, cseg = t >> 5;
    const int m = m0 + r;
    const long srow = (long)(((m >> 10) << 11) + idxm[m]) << 8;
    const float* src = fbuf + srow + (cseg << 5);
    unsigned short* dst = As + r * APITCH + (cseg << 5);
#pragma unroll
    for (int u = 0; u < 8; ++u) {
      const float4 v = *(const float4*)(src + (u << 2));
      const unsigned int lo = bf16rne(v.x) | (bf16rne(v.y) << 16);
      const unsigned int hi = bf16rne(v.z) | (bf16rne(v.w) << 16);
      *(uint2*)(dst + (u << 2)) = make_uint2(lo, hi);
    }
  }

  f32x4 acc[8];
#pragma unroll
  for (int i = 0; i < 8; ++i) acc[i] = (f32x4){0.f, 0.f, 0.f, 0.f};

  // ---- GEMM1: hu = gathered_f @ Wu1 ----
  for (int kc = 0; kc < 8; ++kc) {
    __syncthreads();
    const uint4* sb = (const uint4*)(Wu1P + (((kc << 8) + t) << 5));
    uint4* db = (uint4*)(Bs + t * BPITCH);
    db[0] = sb[0]; db[1] = sb[1]; db[2] = sb[2]; db[3] = sb[3];
    __syncthreads();
    const short8 a = *(const short8*)(As + ((rb << 4) + ln) * APITCH + (kc << 5) + (quad << 3));
#pragma unroll
    for (int nt = 0; nt < 8; ++nt) {
      const int ntg = (ch << 3) + nt;
      const short8 b = *(const short8*)(Bs + ((ntg << 4) + ln) * BPITCH + (quad << 3));
      acc[nt] = __builtin_amdgcn_mfma_f32_16x16x32_bf16(a, b, acc[nt], 0, 0, 0);
    }
  }

  // ---- relu + bias -> Hs (alias As) ----
  __syncthreads();
  unsigned short* Hs = As;
#pragma unroll
  for (int nt = 0; nt < 8; ++nt) {
    const int c = ((ch << 3) + nt << 4) + ln;
    const float bb = bias1[c];
#pragma unroll
    for (int rr = 0; rr < 4; ++rr) {
      const float h = fmaxf(acc[nt][rr] + bb, 0.0f);
      Hs[((rb << 4) + (quad << 2) + rr) * APITCH + c] = (unsigned short)bf16rne(h);
    }
  }
#pragma unroll
  for (int i = 0; i < 8; ++i) acc[i] = (f32x4){0.f, 0.f, 0.f, 0.f};

  // ---- GEMM2: nf = hu @ Wu2 ----
  for (int kc = 0; kc < 8; ++kc) {
    __syncthreads();
    const uint4* sb = (const uint4*)(Wu2P + (((kc << 8) + t) << 5));
    uint4* db = (uint4*)(Bs + t * BPITCH);
    db[0] = sb[0]; db[1] = sb[1]; db[2] = sb[2]; db[3] = sb[3];
    __syncthreads();
    const short8 a = *(const short8*)(Hs + ((rb << 4) + ln) * APITCH + (kc << 5) + (quad << 3));
#pragma unroll
    for (int nt = 0; nt < 8; ++nt) {
      const int ntg = (ch << 3) + nt;
      const short8 b = *(const short8*)(Bs + ((ntg << 4) + ln) * BPITCH + (quad << 3));
      acc[nt] = __builtin_amdgcn_mfma_f32_16x16x32_bf16(a, b, acc[nt], 0, 0, 0);
    }
  }

  // ---- epilogue: +bu2, transpose via T, write out_feat (B,C,K) coalesced ----
  const int bb = m0 >> 10, kbase = m0 & 1023;
  for (int ci = 0; ci < 4; ++ci) {
    __syncthreads();
    if ((ci >> 1) == ch) {
#pragma unroll
      for (int q = 0; q < 4; ++q) {
        const int nt = ((ci & 1) << 2) + q;            // local tile index in this wave
        const int cloc = (q << 4) + ln;                // col within the 64-col group
        const float b2 = bias2[(ci << 6) + cloc];
        const int row = (rb << 4) + (quad << 2);
#pragma unroll
        for (int rr = 0; rr < 4; ++rr)
          T[cloc * 34 + row + rr] = acc[nt][rr] + b2;
      }
    }
    __syncthreads();
#pragma unroll
    for (int p = 0; p < 8; ++p) {
      const int cl = (p << 3) + (t >> 5);
      const int m = t & 31;
      out_feat[((long)((bb << 8) + (ci << 6) + cl) << 10) + kbase + m] = T[cl * 34 + m];
    }
  }
}

extern "C" void kernel_launch(void* const* d_in, const int* in_sizes, int n_in,
                              void* d_out, int out_size, void* d_ws, size_t ws_size,
                              hipStream_t stream) {
  const float* xyzs     = (const float*)d_in[0];
  const float* features = (const float*)d_in[1];
  const float* ln_gamma = (const float*)d_in[2];
  const float* ln_beta  = (const float*)d_in[3];
  const float* Wu1      = (const float*)d_in[4];
  const float* bu1      = (const float*)d_in[5];
  const float* Wu2      = (const float*)d_in[6];
  const float* bu2      = (const float*)d_in[7];
  const float* Wd1      = (const float*)d_in[8];
  const float* bd1      = (const float*)d_in[9];
  const float* Wd2      = (const float*)d_in[10];
  const float* bd2      = (const float*)d_in[11];

  char* ws = (char*)d_ws;
  float* fbuf = (float*)ws;                              // 16 MB
  unsigned short* Wu1P = (unsigned short*)(ws + 33554432);  // 128 KB bf16 slabs
  unsigned short* Wu2P = (unsigned short*)(ws + 33685504);  // 128 KB
  float* wv   = (float*)(ws + 50331648);                 // 16384 f32
  int*   idx  = (int*)(ws + 50397184);                   // 8192 i32

  float* out_xyz  = (float*)d_out;            // (8,1024,3)
  float* out_feat = out_xyz + 24576;          // (8,256,1024)
  float* out_idx  = out_feat + 2097152;       // (8,1024)

  ln_wgemm<<<528, 256, 0, stream>>>(features, ln_gamma, ln_beta, fbuf,
                                    Wd1, bd1, Wd2, bd2, wv,
                                    Wu1, Wu2, Wu1P, Wu2P);
  topk_kernel<<<8, 1024, 0, stream>>>(wv, xyzs, idx, out_xyz, out_idx);
  up_mfma<<<256, 256, 0, stream>>>(fbuf, idx, Wu1P, bu1, Wu2P, bu2, out_feat);
}

// Round 13
// 168.913 us; speedup vs baseline: 1.0169x; 1.0169x over previous
//
#include <hip/hip_runtime.h>

#define B_DIM 8
#define N_DIM 2048
#define C_DIM 256
#define K_SEL 1024

typedef __attribute__((ext_vector_type(8))) short short8;
typedef __attribute__((ext_vector_type(4))) float f32x4;

__device__ __forceinline__ unsigned int bf16rne(float x) {
  unsigned int u = __float_as_uint(x);
  return (u + 0x7fffu + ((u >> 16) & 1u)) >> 16;
}

// ---------------- FUSED LayerNorm + down-GEMM + w-chain (+ prep_w2 tail blocks) ----------------
// FINAL (v14 = v12 revert): ten instrumented K-loop theories falsified (LDS-issue v7,
// A-latency v9, block-overlap v10, LDS-pipe v13, plus 5 spill/scalarize failures v2-v8).
// v13's readlane variant raised VALUBusy 37->46% with zero duration change -> critical
// path is invisible to available counters (barrier/waitcnt drain cadence). Keeping the
// best harness-verified structure: v10 K-loop, 2 blocks/CU, bit-exact chains.
__global__ void __launch_bounds__(256) ln_wgemm(
    const float* __restrict__ feat, const float* __restrict__ gamma,
    const float* __restrict__ beta, float* __restrict__ fbuf,
    const float* __restrict__ Wd1, const float* __restrict__ bd1,
    const float* __restrict__ Wd2, const float* __restrict__ bd2,
    float* __restrict__ wkey,
    const float* __restrict__ Wu1, const float* __restrict__ Wu2,
    unsigned short* __restrict__ Wu1P, unsigned short* __restrict__ Wu2P) {
  __shared__ __align__(16) float tile[256 * 32];       // 32 KB raw x, [c][m ^ (c&31)]
  __shared__ __align__(16) char smem2[2304 + 16640];   // As 16x36x4 | Bs 16x260x4
  __shared__ float murs[64];                           // mu[0:32], rs[32:64]
  __shared__ float gb[512];                            // gamma[0:256], beta[256:512]
  float (*As)[36] = (float (*)[36])smem2;
  float (*Bs)[260] = (float (*)[260])(smem2 + 2304);
  float* H = tile;                                     // 256x32 f32 = 32 KB alias

  const int t = threadIdx.x;

  // ---- prep_w2 tail blocks (verbatim body; independent of LN work) ----
  if (blockIdx.x >= 512) {
    const int g = blockIdx.x - 512;
    const float* W = (g < 8) ? Wu1 : Wu2;
    unsigned short* P = (g < 8) ? Wu1P : Wu2P;
    const int kc = g & 7, n = t;
    unsigned int packed[16];
#pragma unroll
    for (int i = 0; i < 16; ++i) {
      const float a = W[(((kc << 5) + 2 * i) << 8) + n];
      const float bq = W[(((kc << 5) + 2 * i + 1) << 8) + n];
      packed[i] = bf16rne(a) | (bf16rne(bq) << 16);
    }
    uint4* dst = (uint4*)(P + (((kc << 8) + n) << 5));
#pragma unroll
    for (int q = 0; q < 4; ++q)
      dst[q] = make_uint4(packed[4 * q], packed[4 * q + 1], packed[4 * q + 2], packed[4 * q + 3]);
    return;
  }

  const int m0 = blockIdx.x << 5;                      // 32 rows per block
  const int b = m0 >> 11, n0 = m0 & 2047;

  gb[t] = gamma[t];
  gb[256 + t] = beta[t];

  // phase 1: stage raw features
  const int cg = t >> 3, nl4 = (t & 7) << 2;           // cg 0..31, nl4 0..28
  for (int pass = 0; pass < 8; ++pass) {
    const int c = (pass << 5) + cg;
    const float4 v = *(const float4*)(feat + (((long)((b << 8) + c)) << 11) + n0 + nl4);
    const int sw = c & 31;
    float* row = tile + (c << 5);
    row[(nl4 + 0) ^ sw] = v.x; row[(nl4 + 1) ^ sw] = v.y;
    row[(nl4 + 2) ^ sw] = v.z; row[(nl4 + 3) ^ sw] = v.w;
  }
  __syncthreads();

  // phase 2: mean/var per row, numpy-bit-exact chains
  if (t < 32) {
    float acc = tile[t];
    for (int c = 1; c < 256; ++c) acc = __fadd_rn(acc, tile[(c << 5) + (t ^ (c & 31))]);
    const float mu = __fdiv_rn(acc, 256.0f);

    float pw[2];
#pragma unroll
    for (int blk = 0; blk < 2; ++blk) {
      const int c0 = blk << 7;
      float r8[8];
#pragma unroll
      for (int j = 0; j < 8; ++j) {
        float d = __fsub_rn(tile[((c0 + j) << 5) + (t ^ ((c0 + j) & 31))], mu);
        r8[j] = __fmul_rn(d, d);
      }
      for (int i = 8; i < 128; i += 8) {
#pragma unroll
        for (int j = 0; j < 8; ++j) {
          const int c = c0 + i + j;
          float d = __fsub_rn(tile[(c << 5) + (t ^ (c & 31))], mu);
          r8[j] = __fadd_rn(r8[j], __fmul_rn(d, d));
        }
      }
      pw[blk] = __fadd_rn(__fadd_rn(__fadd_rn(r8[0], r8[1]), __fadd_rn(r8[2], r8[3])),
                          __fadd_rn(__fadd_rn(r8[4], r8[5]), __fadd_rn(r8[6], r8[7])));
    }
    const float var = __fdiv_rn(__fadd_rn(pw[0], pw[1]), 256.0f);
    const float rs = __fdiv_rn(1.0f, __fsqrt_rn(__fadd_rn(var, 1e-6f)));
    murs[t] = mu;
    murs[32 + t] = rs;
  }
  __syncthreads();

  // phase 3: write fbuf (one column per thread; coalesced stores)
  {
    const int c = t;
    const float gac = gb[c], bec = gb[256 + c];
    const float* trow = tile + (c << 5);
    const int sw = c & 31;
    for (int r = 0; r < 32; ++r) {
      const float x = trow[r ^ sw];
      const float o = __fadd_rn(
          __fmul_rn(__fmul_rn(__fsub_rn(x, murs[r]), murs[32 + r]), gac), bec);
      fbuf[(((long)(m0 + r)) << 8) + c] = o;
    }
  }

  // phase 4: K-loop (round-0 shape); As staged from tile, normalize folded in
  const int rowT = t >> 6, colT = t & 63;
  const int ar = t & 31, kg4 = (t >> 5) << 2;
  const int bk = t >> 4, bc = (t & 15) << 4;
  const float mu_a = murs[ar], rs_a = murs[32 + ar];
  float acc[8][4] = {};

  for (int k0 = 0; k0 < 256; k0 += 16) {
    if (t < 128) {
#pragma unroll
      for (int q = 0; q < 4; ++q) {
        const int c = k0 + kg4 + q;
        const float x = tile[(c << 5) + (ar ^ (c & 31))];
        As[kg4 + q][ar] = __fadd_rn(
            __fmul_rn(__fmul_rn(__fsub_rn(x, mu_a), rs_a), gb[c]), gb[256 + c]);
      }
    }
    {
      const float* brow = Wd1 + (((k0 + bk) << 8) + bc);
      *(float4*)&Bs[bk][bc]      = *(const float4*)brow;
      *(float4*)&Bs[bk][bc + 4]  = *(const float4*)(brow + 4);
      *(float4*)&Bs[bk][bc + 8]  = *(const float4*)(brow + 8);
      *(float4*)&Bs[bk][bc + 12] = *(const float4*)(brow + 12);
    }
    __syncthreads();
#pragma unroll
    for (int kk = 0; kk < 16; ++kk) {   // k ascending: single FMA chain per (m,c)
      const float4 a0 = *(const float4*)&As[kk][rowT << 3];
      const float4 a1 = *(const float4*)&As[kk][(rowT << 3) + 4];
      const float4 bq = *(const float4*)&Bs[kk][colT << 2];
      const float aa[8] = {a0.x, a0.y, a0.z, a0.w, a1.x, a1.y, a1.z, a1.w};
      const float bbv[4] = {bq.x, bq.y, bq.z, bq.w};
#pragma unroll
      for (int i = 0; i < 8; ++i)
#pragma unroll
        for (int j = 0; j < 4; ++j)
          acc[i][j] = __fmaf_rn(aa[i], bbv[j], acc[i][j]);
    }
    __syncthreads();
  }

  // epilogue: bias + relu -> H[c][m] swizzled
  const float4 bd = *(const float4*)(bd1 + (colT << 2));
  const float ba[4] = {bd.x, bd.y, bd.z, bd.w};
#pragma unroll
  for (int i = 0; i < 8; ++i) {
    const int m = (rowT << 3) + i;
#pragma unroll
    for (int j = 0; j < 4; ++j) {
      const int c = (colT << 2) + j;
      H[(c << 5) + (m ^ ((c >> 2) & 31))] = fmaxf(__fadd_rn(acc[i][j], ba[j]), 0.0f);
    }
  }
  __syncthreads();

  // w-chain: ascending-c single FMA chain; key = (w+bd2)/0.1f
  if (t < 32) {
    float wa = 0.0f;
    for (int c = 0; c < 256; ++c)
      wa = __fmaf_rn(H[(c << 5) + (t ^ ((c >> 2) & 31))], Wd2[c], wa);
    const float w = __fadd_rn(wa, bd2[0]);
    wkey[m0 + t] = __fdiv_rn(w, 0.1f);
  }
}

// ---------------- per-batch top-K: register+shuffle bitonic (v12, verified) ----------------
__global__ void __launch_bounds__(1024) topk_kernel(
    const float* __restrict__ wv, const float* __restrict__ xyzs,
    int* __restrict__ idx_out, float* __restrict__ out_xyz,
    float* __restrict__ out_idx) {
  __shared__ unsigned long long vals[2048];
  const int b = blockIdx.x, t = threadIdx.x;

  unsigned long long a0, a1;
  {
    const float2 w2 = *(const float2*)(wv + (b << 11) + (t << 1));
    const unsigned int u0 = __float_as_uint(w2.x);
    const unsigned int p0 = ((int)u0 < 0) ? ~u0 : (u0 | 0x80000000u);
    a0 = (((unsigned long long)(~p0)) << 32) | (unsigned int)(2 * t);
    const unsigned int u1 = __float_as_uint(w2.y);
    const unsigned int p1 = ((int)u1 < 0) ? ~u1 : (u1 | 0x80000000u);
    a1 = (((unsigned long long)(~p1)) << 32) | (unsigned int)(2 * t + 1);
  }

  for (int k = 2; k <= 2048; k <<= 1) {
    for (int j = k >> 1; j >= 2; j >>= 1) {
      const int x = j >> 1;                       // partner-thread xor distance
      const bool up = (((t << 1) & k) == 0);
      unsigned long long p0, p1;
      if (j >= 128) {                             // cross-wave: via LDS
        vals[2 * t] = a0; vals[2 * t + 1] = a1;
        __syncthreads();
        p0 = vals[(2 * t) ^ j];
        p1 = vals[(2 * t + 1) ^ j];
        __syncthreads();                          // WAR guard for next LDS stage
      } else {                                    // intra-wave: x <= 32
        p0 = __shfl_xor(a0, x, 64);
        p1 = __shfl_xor(a1, x, 64);
      }
      const bool lower = ((t & x) == 0);
      const bool take_min = (lower == up);
      a0 = take_min ? (a0 < p0 ? a0 : p0) : (a0 > p0 ? a0 : p0);
      a1 = take_min ? (a1 < p1 ? a1 : p1) : (a1 > p1 ? a1 : p1);
    }
    {
      const bool up1 = (((t << 1) & k) == 0);
      if ((a0 > a1) == up1) { const unsigned long long tmp = a0; a0 = a1; a1 = tmp; }
    }
  }

  if (t < 512) {
    const int r0 = 2 * t, r1 = 2 * t + 1;
    const int s0 = (int)(a0 & 0xffffffffu);
    const int s1 = (int)(a1 & 0xffffffffu);
    idx_out[(b << 10) + r0] = s0;
    idx_out[(b << 10) + r1] = s1;
    out_idx[(b << 10) + r0] = (float)s0;
    out_idx[(b << 10) + r1] = (float)s1;
    const long o0 = ((long)((b << 10) + r0)) * 3;
    const long q0 = ((long)((b << 11) + s0)) * 3;
    out_xyz[o0] = xyzs[q0]; out_xyz[o0 + 1] = xyzs[q0 + 1]; out_xyz[o0 + 2] = xyzs[q0 + 2];
    const long o1 = ((long)((b << 10) + r1)) * 3;
    const long q1 = ((long)((b << 11) + s1)) * 3;
    out_xyz[o1] = xyzs[q1]; out_xyz[o1 + 1] = xyzs[q1 + 1]; out_xyz[o1 + 2] = xyzs[q1 + 2];
  }
}

// ---------------- fused up-branch: 256 blocks x 32 rows (v11, verified) ----------------
#define APITCH 264
#define BPITCH 40
__global__ void __launch_bounds__(256) up_mfma(
    const float* __restrict__ fbuf, const int* __restrict__ idxm,
    const unsigned short* __restrict__ Wu1P, const float* __restrict__ bu1,
    const unsigned short* __restrict__ Wu2P, const float* __restrict__ bu2,
    float* __restrict__ out_feat) {
  __shared__ __align__(16) char smem[32 * APITCH * 2 + 256 * BPITCH * 2 + 64 * 34 * 4 + 2048];
  unsigned short* As = (unsigned short*)smem;                       // 16896 B (later Hs)
  unsigned short* Bs = (unsigned short*)(smem + 32 * APITCH * 2);   // 20480 B
  float* T = (float*)(smem + 32 * APITCH * 2 + 256 * BPITCH * 2);   // 64x34 f32 = 8704 B
  float* bias1 = (float*)(smem + 32 * APITCH * 2 + 256 * BPITCH * 2 + 64 * 34 * 4);
  float* bias2 = bias1 + 256;

  const int t = threadIdx.x;
  const int m0 = blockIdx.x << 5;                      // 32 rows per block
  const int quad = (t >> 4) & 3, ln = t & 15, w = t >> 6;
  const int rb = w >> 1, ch = w & 1;

  bias1[t] = bu1[t];
  bias2[t] = bu2[t];

  // gather + cvt: As[r][c] bf16, r = t&31, cols (t>>5)*32..+32
  {
    const int r = t & 31, cseg = t >> 5;
    const int m = m0 + r;
    const long srow = (long)(((m >> 10) << 11) + idxm[m]) << 8;
    const float* src = fbuf + srow + (cseg << 5);
    unsigned short* dst = As + r * APITCH + (cseg << 5);
#pragma unroll
    for (int u = 0; u < 8; ++u) {
      const float4 v = *(const float4*)(src + (u << 2));
      const unsigned int lo = bf16rne(v.x) | (bf16rne(v.y) << 16);
      const unsigned int hi = bf16rne(v.z) | (bf16rne(v.w) << 16);
      *(uint2*)(dst + (u << 2)) = make_uint2(lo, hi);
    }
  }

  f32x4 acc[8];
#pragma unroll
  for (int i = 0; i < 8; ++i) acc[i] = (f32x4){0.f, 0.f, 0.f, 0.f};

  // ---- GEMM1: hu = gathered_f @ Wu1 ----
  for (int kc = 0; kc < 8; ++kc) {
    __syncthreads();
    const uint4* sb = (const uint4*)(Wu1P + (((kc << 8) + t) << 5));
    uint4* db = (uint4*)(Bs + t * BPITCH);
    db[0] = sb[0]; db[1] = sb[1]; db[2] = sb[2]; db[3] = sb[3];
    __syncthreads();
    const short8 a = *(const short8*)(As + ((rb << 4) + ln) * APITCH + (kc << 5) + (quad << 3));
#pragma unroll
    for (int nt = 0; nt < 8; ++nt) {
      const int ntg = (ch << 3) + nt;
      const short8 b = *(const short8*)(Bs + ((ntg << 4) + ln) * BPITCH + (quad << 3));
      acc[nt] = __builtin_amdgcn_mfma_f32_16x16x32_bf16(a, b, acc[nt], 0, 0, 0);
    }
  }

  // ---- relu + bias -> Hs (alias As) ----
  __syncthreads();
  unsigned short* Hs = As;
#pragma unroll
  for (int nt = 0; nt < 8; ++nt) {
    const int c = ((ch << 3) + nt << 4) + ln;
    const float bb = bias1[c];
#pragma unroll
    for (int rr = 0; rr < 4; ++rr) {
      const float h = fmaxf(acc[nt][rr] + bb, 0.0f);
      Hs[((rb << 4) + (quad << 2) + rr) * APITCH + c] = (unsigned short)bf16rne(h);
    }
  }
#pragma unroll
  for (int i = 0; i < 8; ++i) acc[i] = (f32x4){0.f, 0.f, 0.f, 0.f};

  // ---- GEMM2: nf = hu @ Wu2 ----
  for (int kc = 0; kc < 8; ++kc) {
    __syncthreads();
    const uint4* sb = (const uint4*)(Wu2P + (((kc << 8) + t) << 5));
    uint4* db = (uint4*)(Bs + t * BPITCH);
    db[0] = sb[0]; db[1] = sb[1]; db[2] = sb[2]; db[3] = sb[3];
    __syncthreads();
    const short8 a = *(const short8*)(Hs + ((rb << 4) + ln) * APITCH + (kc << 5) + (quad << 3));
#pragma unroll
    for (int nt = 0; nt < 8; ++nt) {
      const int ntg = (ch << 3) + nt;
      const short8 b = *(const short8*)(Bs + ((ntg << 4) + ln) * BPITCH + (quad << 3));
      acc[nt] = __builtin_amdgcn_mfma_f32_16x16x32_bf16(a, b, acc[nt], 0, 0, 0);
    }
  }

  // ---- epilogue: +bu2, transpose via T, write out_feat (B,C,K) coalesced ----
  const int bb = m0 >> 10, kbase = m0 & 1023;
  for (int ci = 0; ci < 4; ++ci) {
    __syncthreads();
    if ((ci >> 1) == ch) {
#pragma unroll
      for (int q = 0; q < 4; ++q) {
        const int nt = ((ci & 1) << 2) + q;            // local tile index in this wave
        const int cloc = (q << 4) + ln;                // col within the 64-col group
        const float b2 = bias2[(ci << 6) + cloc];
        const int row = (rb << 4) + (quad << 2);
#pragma unroll
        for (int rr = 0; rr < 4; ++rr)
          T[cloc * 34 + row + rr] = acc[nt][rr] + b2;
      }
    }
    __syncthreads();
#pragma unroll
    for (int p = 0; p < 8; ++p) {
      const int cl = (p << 3) + (t >> 5);
      const int m = t & 31;
      out_feat[((long)((bb << 8) + (ci << 6) + cl) << 10) + kbase + m] = T[cl * 34 + m];
    }
  }
}

extern "C" void kernel_launch(void* const* d_in, const int* in_sizes, int n_in,
                              void* d_out, int out_size, void* d_ws, size_t ws_size,
                              hipStream_t stream) {
  const float* xyzs     = (const float*)d_in[0];
  const float* features = (const float*)d_in[1];
  const float* ln_gamma = (const float*)d_in[2];
  const float* ln_beta  = (const float*)d_in[3];
  const float* Wu1      = (const float*)d_in[4];
  const float* bu1      = (const float*)d_in[5];
  const float* Wu2      = (const float*)d_in[6];
  const float* bu2      = (const float*)d_in[7];
  const float* Wd1      = (const float*)d_in[8];
  const float* bd1      = (const float*)d_in[9];
  const float* Wd2      = (const float*)d_in[10];
  const float* bd2      = (const float*)d_in[11];

  char* ws = (char*)d_ws;
  float* fbuf = (float*)ws;                              // 16 MB
  unsigned short* Wu1P = (unsigned short*)(ws + 33554432);  // 128 KB bf16 slabs
  unsigned short* Wu2P = (unsigned short*)(ws + 33685504);  // 128 KB
  float* wv   = (float*)(ws + 50331648);                 // 16384 f32
  int*   idx  = (int*)(ws + 50397184);                   // 8192 i32

  float* out_xyz  = (float*)d_out;            // (8,1024,3)
  float* out_feat = out_xyz + 24576;          // (8,256,1024)
  float* out_idx  = out_feat + 2097152;       // (8,1024)

  ln_wgemm<<<528, 256, 0, stream>>>(features, ln_gamma, ln_beta, fbuf,
                                    Wd1, bd1, Wd2, bd2, wv,
                                    Wu1, Wu2, Wu1P, Wu2P);
  topk_kernel<<<8, 1024, 0, stream>>>(wv, xyzs, idx, out_xyz, out_idx);
  up_mfma<<<256, 256, 0, stream>>>(fbuf, idx, Wu1P, bu1, Wu2P, bu2, out_feat);
}